// Round 2
// baseline (2742.511 us; speedup 1.0000x reference)
//
#include <hip/hip_runtime.h>

#define HWSZ 65536   // 256*256
#define CCH  64
#define NB   2

// ---------------------------------------------------------------------------
// 1x1 conv (residual): out[b,o,hw] = sum_i w[o,i]*x[b,i,hw] + bias[o]
// ---------------------------------------------------------------------------
__global__ __launch_bounds__(256) void k_conv1x1(
    const float* __restrict__ x, const float* __restrict__ w,
    const float* __restrict__ bias, float* __restrict__ out)
{
    __shared__ __align__(16) float lwT[4096];   // [i][o]
    __shared__ float lb[64];
    int t = threadIdx.x;
    for (int s = t; s < 4096; s += 256) lwT[s] = w[(s & 63) * 64 + (s >> 6)];
    if (t < 64) lb[t] = bias[t];
    __syncthreads();

    int p  = blockIdx.x * 256 + t;      // 0..131071
    int b  = p >> 16, hw = p & 65535;
    const float* xp = x + (size_t)b * CCH * HWSZ + hw;

    float acc[64];
    #pragma unroll
    for (int o = 0; o < 64; ++o) acc[o] = lb[o];

    #pragma unroll 4
    for (int i = 0; i < 64; ++i) {
        float xi = xp[(size_t)i * HWSZ];
        const float4* w4 = (const float4*)&lwT[i * 64];
        #pragma unroll
        for (int o4 = 0; o4 < 16; ++o4) {
            float4 wv = w4[o4];
            acc[o4*4+0] += wv.x * xi;
            acc[o4*4+1] += wv.y * xi;
            acc[o4*4+2] += wv.z * xi;
            acc[o4*4+3] += wv.w * xi;
        }
    }
    float* op = out + (size_t)b * CCH * HWSZ + hw;
    #pragma unroll
    for (int o = 0; o < 64; ++o) op[(size_t)o * HWSZ] = acc[o];
}

// ---------------------------------------------------------------------------
// 3x3 conv, 64->64, pad 1. 16x16 spatial tile, 64 out-channel acc/thread.
// ---------------------------------------------------------------------------
template<int RELU>
__global__ __launch_bounds__(256) void k_conv3x3(
    const float* __restrict__ x, const float* __restrict__ w,
    const float* __restrict__ bias, float* __restrict__ out)
{
    __shared__ __align__(16) float lx[18 * 20];      // stride 20
    __shared__ __align__(16) float lw[64 * 12];      // [o][12] padded

    int t  = threadIdx.x;
    int tx = t & 15, ty = t >> 4;
    int w0 = blockIdx.x * 16, h0 = blockIdx.y * 16;
    int b  = blockIdx.z;

    float acc[64];
    #pragma unroll
    for (int o = 0; o < 64; ++o) acc[o] = bias[o];

    const float* xb = x + (size_t)b * CCH * HWSZ;

    for (int i = 0; i < 64; ++i) {
        const float* xc = xb + (size_t)i * HWSZ;
        for (int s = t; s < 18 * 18; s += 256) {
            int sy = s / 18, sx = s - sy * 18;
            int gy = h0 + sy - 1, gx = w0 + sx - 1;
            float v = 0.f;
            if ((unsigned)gy < 256u && (unsigned)gx < 256u) v = xc[gy * 256 + gx];
            lx[sy * 20 + sx] = v;
        }
        for (int s = t; s < 576; s += 256) {
            int o = s / 9, k = s - o * 9;
            lw[o * 12 + k] = w[((size_t)o * 64 + i) * 9 + k];
        }
        __syncthreads();

        float p[9];
        #pragma unroll
        for (int dy = 0; dy < 3; ++dy)
            #pragma unroll
            for (int dx = 0; dx < 3; ++dx)
                p[dy*3+dx] = lx[(ty + dy) * 20 + tx + dx];

        #pragma unroll
        for (int o = 0; o < 64; ++o) {
            const float4* wv = (const float4*)&lw[o * 12];
            float4 wa = wv[0], wb = wv[1];
            float  w8 = lw[o * 12 + 8];
            acc[o] += wa.x*p[0] + wa.y*p[1] + wa.z*p[2] + wa.w*p[3]
                    + wb.x*p[4] + wb.y*p[5] + wb.z*p[6] + wb.w*p[7] + w8*p[8];
        }
        __syncthreads();
    }

    int h = h0 + ty, wc = w0 + tx;
    float* op = out + (size_t)b * CCH * HWSZ + h * 256 + wc;
    #pragma unroll
    for (int o = 0; o < 64; ++o) {
        float v = acc[o];
        if (RELU) v = v > 0.f ? v : 0.01f * v;
        op[(size_t)o * HWSZ] = v;
    }
}

// ---------------------------------------------------------------------------
// 5x5 conv, 64->64, pad 2.
// ---------------------------------------------------------------------------
template<int RELU>
__global__ __launch_bounds__(256) void k_conv5x5_64(
    const float* __restrict__ x, const float* __restrict__ w,
    const float* __restrict__ bias, float* __restrict__ out)
{
    __shared__ __align__(16) float lx[400];          // 20x20
    __shared__ __align__(16) float lw[64 * 28];      // [o][28] padded

    int t  = threadIdx.x;
    int tx = t & 15, ty = t >> 4;
    int w0 = blockIdx.x * 16, h0 = blockIdx.y * 16;
    int b  = blockIdx.z;

    float acc[64];
    #pragma unroll
    for (int o = 0; o < 64; ++o) acc[o] = bias[o];

    const float* xb = x + (size_t)b * CCH * HWSZ;

    for (int i = 0; i < 64; ++i) {
        const float* xc = xb + (size_t)i * HWSZ;
        for (int s = t; s < 400; s += 256) {
            int sy = s / 20, sx = s - sy * 20;
            int gy = h0 + sy - 2, gx = w0 + sx - 2;
            float v = 0.f;
            if ((unsigned)gy < 256u && (unsigned)gx < 256u) v = xc[gy * 256 + gx];
            lx[s] = v;
        }
        for (int s = t; s < 1600; s += 256) {
            int o = s / 25, k = s - o * 25;
            lw[o * 28 + k] = w[((size_t)o * 64 + i) * 25 + k];
        }
        __syncthreads();

        float p[25];
        #pragma unroll
        for (int dy = 0; dy < 5; ++dy)
            #pragma unroll
            for (int dx = 0; dx < 5; ++dx)
                p[dy*5+dx] = lx[(ty + dy) * 20 + tx + dx];

        #pragma unroll
        for (int o = 0; o < 64; ++o) {
            const float4* wv = (const float4*)&lw[o * 28];
            float4 a0 = wv[0], a1 = wv[1], a2 = wv[2], a3 = wv[3], a4 = wv[4], a5 = wv[5];
            float  a6 = lw[o * 28 + 24];
            float s0 = a0.x*p[0]  + a0.y*p[1]  + a0.z*p[2]  + a0.w*p[3];
            float s1 = a1.x*p[4]  + a1.y*p[5]  + a1.z*p[6]  + a1.w*p[7];
            float s2 = a2.x*p[8]  + a2.y*p[9]  + a2.z*p[10] + a2.w*p[11];
            float s3 = a3.x*p[12] + a3.y*p[13] + a3.z*p[14] + a3.w*p[15];
            float s4 = a4.x*p[16] + a4.y*p[17] + a4.z*p[18] + a4.w*p[19];
            float s5 = a5.x*p[20] + a5.y*p[21] + a5.z*p[22] + a5.w*p[23];
            acc[o] += s0 + s1 + s2 + s3 + s4 + s5 + a6*p[24];
        }
        __syncthreads();
    }

    int h = h0 + ty, wc = w0 + tx;
    float* op = out + (size_t)b * CCH * HWSZ + h * 256 + wc;
    #pragma unroll
    for (int o = 0; o < 64; ++o) {
        float v = acc[o];
        if (RELU) v = v > 0.f ? v : 0.01f * v;
        op[(size_t)o * HWSZ] = v;
    }
}

// ---------------------------------------------------------------------------
// 5x5 conv, 64->9, pad 2 (adaptive-weight generator).
// ---------------------------------------------------------------------------
__global__ __launch_bounds__(256) void k_conv5x5_9(
    const float* __restrict__ x, const float* __restrict__ w,
    const float* __restrict__ bias, float* __restrict__ out)
{
    __shared__ __align__(16) float lx[400];
    __shared__ __align__(16) float lw[9 * 28];

    int t  = threadIdx.x;
    int tx = t & 15, ty = t >> 4;
    int w0 = blockIdx.x * 16, h0 = blockIdx.y * 16;
    int b  = blockIdx.z;

    float acc[9];
    #pragma unroll
    for (int o = 0; o < 9; ++o) acc[o] = bias[o];

    const float* xb = x + (size_t)b * CCH * HWSZ;

    for (int i = 0; i < 64; ++i) {
        const float* xc = xb + (size_t)i * HWSZ;
        for (int s = t; s < 400; s += 256) {
            int sy = s / 20, sx = s - sy * 20;
            int gy = h0 + sy - 2, gx = w0 + sx - 2;
            float v = 0.f;
            if ((unsigned)gy < 256u && (unsigned)gx < 256u) v = xc[gy * 256 + gx];
            lx[s] = v;
        }
        for (int s = t; s < 225; s += 256) {
            int o = s / 25, k = s - o * 25;
            lw[o * 28 + k] = w[((size_t)o * 64 + i) * 25 + k];
        }
        __syncthreads();

        float p[25];
        #pragma unroll
        for (int dy = 0; dy < 5; ++dy)
            #pragma unroll
            for (int dx = 0; dx < 5; ++dx)
                p[dy*5+dx] = lx[(ty + dy) * 20 + tx + dx];

        #pragma unroll
        for (int o = 0; o < 9; ++o) {
            const float4* wv = (const float4*)&lw[o * 28];
            float4 a0 = wv[0], a1 = wv[1], a2 = wv[2], a3 = wv[3], a4 = wv[4], a5 = wv[5];
            float  a6 = lw[o * 28 + 24];
            float s0 = a0.x*p[0]  + a0.y*p[1]  + a0.z*p[2]  + a0.w*p[3];
            float s1 = a1.x*p[4]  + a1.y*p[5]  + a1.z*p[6]  + a1.w*p[7];
            float s2 = a2.x*p[8]  + a2.y*p[9]  + a2.z*p[10] + a2.w*p[11];
            float s3 = a3.x*p[12] + a3.y*p[13] + a3.z*p[14] + a3.w*p[15];
            float s4 = a4.x*p[16] + a4.y*p[17] + a4.z*p[18] + a4.w*p[19];
            float s5 = a5.x*p[20] + a5.y*p[21] + a5.z*p[22] + a5.w*p[23];
            acc[o] += s0 + s1 + s2 + s3 + s4 + s5 + a6*p[24];
        }
        __syncthreads();
    }

    int h = h0 + ty, wc = w0 + tx;
    float* op = out + (size_t)b * 9 * HWSZ + h * 256 + wc;
    #pragma unroll
    for (int o = 0; o < 9; ++o) op[(size_t)o * HWSZ] = acc[o];
}

// ---------------------------------------------------------------------------
// Adaptive einsum: out[b,c,h,w] = lrelu( sum_k wgt[b,k,h,w]*xin[b,c,h+dy,w+dx] )
// (+ in-place residual add when ADDRES).
// ---------------------------------------------------------------------------
template<int ADDRES>
__global__ __launch_bounds__(256) void k_ada(
    const float* __restrict__ wgt, const float* __restrict__ xin,
    float* __restrict__ out)
{
    int p  = blockIdx.x * 256 + threadIdx.x;
    int b  = p >> 16, hw = p & 65535;
    int h  = hw >> 8, wc = hw & 255;

    const float* wp = wgt + (size_t)b * 9 * HWSZ + hw;
    float wk[9];
    #pragma unroll
    for (int k = 0; k < 9; ++k) wk[k] = wp[(size_t)k * HWSZ];

    bool oky[3], okx[3];
    #pragma unroll
    for (int d = 0; d < 3; ++d) {
        oky[d] = (unsigned)(h  + d - 1) < 256u;
        okx[d] = (unsigned)(wc + d - 1) < 256u;
    }

    const float* xb = xin + (size_t)b * CCH * HWSZ;
    float*       ob = out + (size_t)b * CCH * HWSZ;

    for (int c = 0; c < 64; ++c) {
        const float* xc = xb + (size_t)c * HWSZ;
        float s = 0.f;
        #pragma unroll
        for (int dy = 0; dy < 3; ++dy) {
            #pragma unroll
            for (int dx = 0; dx < 3; ++dx) {
                float v = (oky[dy] && okx[dx]) ? xc[(h+dy-1)*256 + (wc+dx-1)] : 0.f;
                s += wk[dy*3+dx] * v;
            }
        }
        s = s > 0.f ? s : 0.01f * s;
        size_t oi = (size_t)c * HWSZ + hw;
        if (ADDRES) ob[oi] = s + ob[oi];
        else        ob[oi] = s;
    }
}

// ---------------------------------------------------------------------------
// Buffer plan (fits in 38.3 MB of d_ws — round-0 OOB fix):
//   wgt  = ws[0 .. 1179648)                 4.7 MB  (adaptive weights)
//   bufb = ws + 1179648  (8388608 floats)  33.5 MB  (xa / maska)
//   bufa = out_m half of d_out             33.5 MB  (x1 / x2 scratch;
//          final mask written by step 9, the last kernel that touches it)
// ---------------------------------------------------------------------------
extern "C" void kernel_launch(void* const* d_in, const int* in_sizes, int n_in,
                              void* d_out, int out_size, void* d_ws, size_t ws_size,
                              hipStream_t stream)
{
    const float* x     = (const float*)d_in[0];
    const float* mask  = (const float*)d_in[1];
    const float* aw1_w = (const float*)d_in[2];
    const float* aw1_b = (const float*)d_in[3];
    const float* mt1_w = (const float*)d_in[4];
    const float* mt1_b = (const float*)d_in[5];
    const float* c1_w  = (const float*)d_in[6];
    const float* c1_b  = (const float*)d_in[7];
    const float* aw2_w = (const float*)d_in[8];
    const float* aw2_b = (const float*)d_in[9];
    const float* mt2_w = (const float*)d_in[10];
    const float* mt2_b = (const float*)d_in[11];
    const float* c2_w  = (const float*)d_in[12];
    const float* c2_b  = (const float*)d_in[13];
    const float* cr_w  = (const float*)d_in[14];
    const float* cr_b  = (const float*)d_in[15];

    float* out_x = (float*)d_out;                  // 8388608 floats
    float* out_m = (float*)d_out + 8388608;

    float* ws   = (float*)d_ws;
    float* wgt  = ws;                 // 1179648 floats
    float* bufb = ws + 1179648;       // 8388608 floats (ws total: 38.3 MB)
    float* bufa = out_m;              // scratch until step 9 overwrites it

    dim3 blk(256);
    dim3 gconv(16, 16, 2);
    dim3 gpix(512);

    // 1. res = conv1x1(x) -> out_x (consumed in-place by step 8)
    k_conv1x1<<<gpix, blk, 0, stream>>>(x, cr_w, cr_b, out_x);
    // 2. weight1 = conv5x5_9(mask, aw1) -> wgt
    k_conv5x5_9<<<gconv, blk, 0, stream>>>(mask, aw1_w, aw1_b, wgt);
    // 3. x1 = conv3x3(x, c1) -> bufa (= out_m scratch)
    k_conv3x3<0><<<gconv, blk, 0, stream>>>(x, c1_w, c1_b, bufa);
    // 4. xa = lrelu(ada(weight1, x1)) -> bufb
    k_ada<0><<<gpix, blk, 0, stream>>>(wgt, bufa, bufb);
    // 5. x2 = conv3x3(xa, c2) -> bufa
    k_conv3x3<0><<<gconv, blk, 0, stream>>>(bufb, c2_w, c2_b, bufa);
    // 6. maska = lrelu(conv5x5(mask, mt1)) -> bufb
    k_conv5x5_64<1><<<gconv, blk, 0, stream>>>(mask, mt1_w, mt1_b, bufb);
    // 7. weight2 = conv5x5_9(maska, aw2) -> wgt
    k_conv5x5_9<<<gconv, blk, 0, stream>>>(bufb, aw2_w, aw2_b, wgt);
    // 8. out_x = lrelu(ada(weight2, x2)) + res   (in-place add)
    k_ada<1><<<gpix, blk, 0, stream>>>(wgt, bufa, out_x);
    // 9. out_m = lrelu(conv5x5(maska, mt2))  (overwrites bufa scratch)
    k_conv5x5_64<1><<<gconv, blk, 0, stream>>>(bufb, mt2_w, mt2_b, out_m);
}

// Round 3
// 460.559 us; speedup vs baseline: 5.9547x; 5.9547x over previous
//
#include <hip/hip_runtime.h>

#define HWSZ 65536   // 256*256
#define CCH  64

typedef __bf16 bf16x8 __attribute__((ext_vector_type(8)));
typedef float  f32x4  __attribute__((ext_vector_type(4)));

// ---------------------------------------------------------------------------
// Weight prep: f32 src [OC][64][KK] (KK = ksz*ksz, k-minor) -> bf16 dst
// [KK][OROWS][64] with OROWS = 16 (OC=9, zero-padded) or 64.
// ---------------------------------------------------------------------------
template<int KK, int OC>
__global__ __launch_bounds__(256) void k_prep(
    const float* __restrict__ src, __bf16* __restrict__ dst)
{
    constexpr int OROWS = (OC == 9) ? 16 : 64;
    int t = blockIdx.x * 256 + threadIdx.x;
    if (t >= KK * OROWS * 64) return;
    int i = t & 63;
    int o = (t >> 6) % OROWS;
    int k = t / (OROWS * 64);
    float v = (o < OC) ? src[((size_t)o * 64 + i) * KK + k] : 0.f;
    dst[t] = (__bf16)v;
}

// ---------------------------------------------------------------------------
// MFMA implicit-GEMM conv: KSZ in {3,5}, MF m-frags (4 -> 64 out-ch, 1 -> 9),
// optional leaky-relu. Block = 16x16 pixel tile, 4 waves, each wave computes
// M = MF*16 out-ch x N = 64 pixels (4 rows) via mfma_f32_16x16x32_bf16.
// LDS: x-tile [pix][64ch] bf16 (128 B rows, XOR-swizzled 16B slots, T2/G4),
//      per-offset W [o][64i] bf16 (same swizzle).
// ---------------------------------------------------------------------------
template<int KSZ, int MF, int RELU>
__global__ __launch_bounds__(256) void k_mconv(
    const float* __restrict__ x, const __bf16* __restrict__ wb,
    const float* __restrict__ bias, float* __restrict__ out)
{
    constexpr int PAD   = KSZ / 2;
    constexpr int TW    = 16 + 2 * PAD;     // 18 or 20
    constexpr int NPIX  = TW * TW;          // 324 or 400
    constexpr int KK    = KSZ * KSZ;        // 9 or 25
    constexpr int OROWS = MF * 16;          // 16 or 64
    constexpr int OUTC  = (MF == 1) ? 9 : 64;

    __shared__ __align__(16) __bf16 lx[NPIX * 64];   // swizzled 128-B rows
    __shared__ __align__(16) __bf16 lw[OROWS * 64];  // swizzled 128-B rows
    __shared__ float lb[64];

    const int t    = threadIdx.x;
    const int w0   = blockIdx.x * 16, h0 = blockIdx.y * 16, b = blockIdx.z;
    const int wv   = t >> 6;
    const int lane = t & 63;
    const int px   = lane & 15;       // N-col / A-row selector
    const int g    = lane >> 4;       // k-group 0..3

    if (t < 64) lb[t] = (t < OUTC) ? bias[t] : 0.f;

    // ---- stage x tile: global f32 [c][gy][gx] -> LDS bf16 [pix][c] swizzled
    const float* xb = x + (size_t)b * CCH * HWSZ;
    for (int e = t; e < NPIX * 64; e += 256) {
        int c   = e / NPIX;
        int pix = e - c * NPIX;
        int sy  = pix / TW, sx = pix - sy * TW;
        int gy  = h0 + sy - PAD, gx = w0 + sx - PAD;
        float v = 0.f;
        if ((unsigned)gy < 256u && (unsigned)gx < 256u)
            v = xb[(size_t)c * HWSZ + gy * 256 + gx];
        int byteoff = (pix << 7) + (((c << 1)) ^ ((pix & 7) << 4));
        *(__bf16*)((char*)lx + byteoff) = (__bf16)v;
    }

    f32x4 acc[MF][4];
    #pragma unroll
    for (int m = 0; m < MF; ++m)
        #pragma unroll
        for (int nf = 0; nf < 4; ++nf)
            acc[m][nf] = (f32x4){0.f, 0.f, 0.f, 0.f};

    for (int k = 0; k < KK; ++k) {
        __syncthreads();   // x/lb staged (iter 0); lw free of readers (iter>0)
        // ---- stage W slice for this offset: [OROWS][64] bf16, swizzled
        const __bf16* wsrc = wb + (size_t)k * (OROWS * 64);
        for (int ch = t; ch < OROWS * 8; ch += 256) {
            int o = ch >> 3, s = ch & 7;
            uint4 val = ((const uint4*)wsrc)[ch];
            int byteoff = (o << 7) + (((s << 4)) ^ ((o & 7) << 4));
            *(uint4*)((char*)lw + byteoff) = val;
        }
        __syncthreads();

        const int dy = k / KSZ, dx = k - dy * KSZ;

        bf16x8 bfr[4][2];
        #pragma unroll
        for (int nf = 0; nf < 4; ++nf) {
            int pix = (wv * 4 + nf + dy) * TW + (px + dx);
            int rowbase = pix << 7, sw = (pix & 7) << 4;
            #pragma unroll
            for (int ks = 0; ks < 2; ++ks) {
                int s = ks * 4 + g;
                bfr[nf][ks] = *(const bf16x8*)((const char*)lx + rowbase + ((s << 4) ^ sw));
            }
        }
        bf16x8 afr[MF][2];
        #pragma unroll
        for (int m = 0; m < MF; ++m) {
            int o = m * 16 + px;
            int rowbase = o << 7, sw = (o & 7) << 4;
            #pragma unroll
            for (int ks = 0; ks < 2; ++ks) {
                int s = ks * 4 + g;
                afr[m][ks] = *(const bf16x8*)((const char*)lw + rowbase + ((s << 4) ^ sw));
            }
        }
        #pragma unroll
        for (int m = 0; m < MF; ++m)
            #pragma unroll
            for (int nf = 0; nf < 4; ++nf)
                #pragma unroll
                for (int ks = 0; ks < 2; ++ks)
                    acc[m][nf] = __builtin_amdgcn_mfma_f32_16x16x32_bf16(
                        afr[m][ks], bfr[nf][ks], acc[m][nf], 0, 0, 0);
    }

    // ---- epilogue: D row = g*4+j (+16*m), col = px
    float* ob = out + (size_t)b * OUTC * HWSZ;
    #pragma unroll
    for (int m = 0; m < MF; ++m)
        #pragma unroll
        for (int nf = 0; nf < 4; ++nf) {
            int row = h0 + wv * 4 + nf, col = w0 + px;
            #pragma unroll
            for (int j = 0; j < 4; ++j) {
                int o = m * 16 + g * 4 + j;
                if (o < OUTC) {
                    float v = acc[m][nf][j] + lb[o];
                    if (RELU) v = v > 0.f ? v : 0.01f * v;
                    ob[(size_t)o * HWSZ + row * 256 + col] = v;
                }
            }
        }
}

// ---------------------------------------------------------------------------
// 1x1 conv (residual), f32 (memory-bound).
// ---------------------------------------------------------------------------
__global__ __launch_bounds__(256) void k_conv1x1(
    const float* __restrict__ x, const float* __restrict__ w,
    const float* __restrict__ bias, float* __restrict__ out)
{
    __shared__ __align__(16) float lwT[4096];   // [i][o]
    __shared__ float lb[64];
    int t = threadIdx.x;
    for (int s = t; s < 4096; s += 256) lwT[s] = w[(s & 63) * 64 + (s >> 6)];
    if (t < 64) lb[t] = bias[t];
    __syncthreads();

    int p  = blockIdx.x * 256 + t;
    int b  = p >> 16, hw = p & 65535;
    const float* xp = x + (size_t)b * CCH * HWSZ + hw;

    float acc[64];
    #pragma unroll
    for (int o = 0; o < 64; ++o) acc[o] = lb[o];

    #pragma unroll 4
    for (int i = 0; i < 64; ++i) {
        float xi = xp[(size_t)i * HWSZ];
        const float4* w4 = (const float4*)&lwT[i * 64];
        #pragma unroll
        for (int o4 = 0; o4 < 16; ++o4) {
            float4 wv = w4[o4];
            acc[o4*4+0] += wv.x * xi;
            acc[o4*4+1] += wv.y * xi;
            acc[o4*4+2] += wv.z * xi;
            acc[o4*4+3] += wv.w * xi;
        }
    }
    float* op = out + (size_t)b * CCH * HWSZ + hw;
    #pragma unroll
    for (int o = 0; o < 64; ++o) op[(size_t)o * HWSZ] = acc[o];
}

// ---------------------------------------------------------------------------
// Adaptive einsum (+ optional in-place residual add), f32 (memory-bound).
// ---------------------------------------------------------------------------
template<int ADDRES>
__global__ __launch_bounds__(256) void k_ada(
    const float* __restrict__ wgt, const float* __restrict__ xin,
    float* __restrict__ out)
{
    int p  = blockIdx.x * 256 + threadIdx.x;
    int b  = p >> 16, hw = p & 65535;
    int h  = hw >> 8, wc = hw & 255;

    const float* wp = wgt + (size_t)b * 9 * HWSZ + hw;
    float wk[9];
    #pragma unroll
    for (int k = 0; k < 9; ++k) wk[k] = wp[(size_t)k * HWSZ];

    bool oky[3], okx[3];
    #pragma unroll
    for (int d = 0; d < 3; ++d) {
        oky[d] = (unsigned)(h  + d - 1) < 256u;
        okx[d] = (unsigned)(wc + d - 1) < 256u;
    }

    const float* xb = xin + (size_t)b * CCH * HWSZ;
    float*       ob = out + (size_t)b * CCH * HWSZ;

    for (int c = 0; c < 64; ++c) {
        const float* xc = xb + (size_t)c * HWSZ;
        float s = 0.f;
        #pragma unroll
        for (int dy = 0; dy < 3; ++dy)
            #pragma unroll
            for (int dx = 0; dx < 3; ++dx) {
                float v = (oky[dy] && okx[dx]) ? xc[(h+dy-1)*256 + (wc+dx-1)] : 0.f;
                s += wk[dy*3+dx] * v;
            }
        s = s > 0.f ? s : 0.01f * s;
        size_t oi = (size_t)c * HWSZ + hw;
        if (ADDRES) ob[oi] = s + ob[oi];
        else        ob[oi] = s;
    }
}

// ---------------------------------------------------------------------------
// ws layout (38.93 MB total):
//   wgt   f32  @0          1179648 floats ( 4.50 MB)  adaptive weights
//   bufb  f32  @1179648    8388608 floats (32.00 MB)  xa / maska
//   wb    bf16 @38273024 B  329728 elems  ( 0.63 MB)  prepped conv weights
//   bufa = out_m half of d_out (scratch until final kernel overwrites it)
// ---------------------------------------------------------------------------
extern "C" void kernel_launch(void* const* d_in, const int* in_sizes, int n_in,
                              void* d_out, int out_size, void* d_ws, size_t ws_size,
                              hipStream_t stream)
{
    const float* x     = (const float*)d_in[0];
    const float* mask  = (const float*)d_in[1];
    const float* aw1_w = (const float*)d_in[2];
    const float* aw1_b = (const float*)d_in[3];
    const float* mt1_w = (const float*)d_in[4];
    const float* mt1_b = (const float*)d_in[5];
    const float* c1_w  = (const float*)d_in[6];
    const float* c1_b  = (const float*)d_in[7];
    const float* aw2_w = (const float*)d_in[8];
    const float* aw2_b = (const float*)d_in[9];
    const float* mt2_w = (const float*)d_in[10];
    const float* mt2_b = (const float*)d_in[11];
    const float* c2_w  = (const float*)d_in[12];
    const float* c2_b  = (const float*)d_in[13];
    const float* cr_w  = (const float*)d_in[14];
    const float* cr_b  = (const float*)d_in[15];

    float* out_x = (float*)d_out;
    float* out_m = (float*)d_out + 8388608;

    float*  ws   = (float*)d_ws;
    float*  wgt  = ws;
    float*  bufb = ws + 1179648;
    float*  bufa = out_m;   // scratch until step 10 overwrites it
    __bf16* wbase = (__bf16*)((char*)d_ws + 38273024);
    __bf16* wb_c1  = wbase;            // [9][64][64]   36864
    __bf16* wb_c2  = wbase + 36864;    // [9][64][64]   36864
    __bf16* wb_mt1 = wbase + 73728;    // [25][64][64] 102400
    __bf16* wb_mt2 = wbase + 176128;   // [25][64][64] 102400
    __bf16* wb_aw1 = wbase + 278528;   // [25][16][64]  25600
    __bf16* wb_aw2 = wbase + 304128;   // [25][16][64]  25600

    dim3 blk(256);
    dim3 gconv(16, 16, 2);
    dim3 gpix(512);

    // 0. weight prep (bf16, MFMA layouts)
    k_prep<9, 64><<<144, blk, 0, stream>>>(c1_w,  wb_c1);
    k_prep<9, 64><<<144, blk, 0, stream>>>(c2_w,  wb_c2);
    k_prep<25,64><<<400, blk, 0, stream>>>(mt1_w, wb_mt1);
    k_prep<25,64><<<400, blk, 0, stream>>>(mt2_w, wb_mt2);
    k_prep<25, 9><<<100, blk, 0, stream>>>(aw1_w, wb_aw1);
    k_prep<25, 9><<<100, blk, 0, stream>>>(aw2_w, wb_aw2);

    // 1. res = conv1x1(x) -> out_x (consumed in-place by step 8)
    k_conv1x1<<<gpix, blk, 0, stream>>>(x, cr_w, cr_b, out_x);
    // 2. weight1 = conv5x5_9(mask, aw1) -> wgt
    k_mconv<5,1,0><<<gconv, blk, 0, stream>>>(mask, wb_aw1, aw1_b, wgt);
    // 3. x1 = conv3x3(x, c1) -> bufa
    k_mconv<3,4,0><<<gconv, blk, 0, stream>>>(x, wb_c1, c1_b, bufa);
    // 4. xa = lrelu(ada(weight1, x1)) -> bufb
    k_ada<0><<<gpix, blk, 0, stream>>>(wgt, bufa, bufb);
    // 5. x2 = conv3x3(xa, c2) -> bufa
    k_mconv<3,4,0><<<gconv, blk, 0, stream>>>(bufb, wb_c2, c2_b, bufa);
    // 6. maska = lrelu(conv5x5(mask, mt1)) -> bufb
    k_mconv<5,4,1><<<gconv, blk, 0, stream>>>(mask, wb_mt1, mt1_b, bufb);
    // 7. weight2 = conv5x5_9(maska, aw2) -> wgt
    k_mconv<5,1,0><<<gconv, blk, 0, stream>>>(bufb, wb_aw2, aw2_b, wgt);
    // 8. out_x = lrelu(ada(weight2, x2)) + res   (in-place add)
    k_ada<1><<<gpix, blk, 0, stream>>>(wgt, bufa, out_x);
    // 9. out_m = lrelu(conv5x5(maska, mt2))  (overwrites bufa scratch)
    k_mconv<5,4,1><<<gconv, blk, 0, stream>>>(bufb, wb_mt2, mt2_b, out_m);
}